// Round 1
// baseline (4767.743 us; speedup 1.0000x reference)
//
#include <hip/hip_runtime.h>

#define NHEAD 8
#define DK 64
#define DMODEL 512
#define LSEQ 1000

// ---------------- LayerNorm: one block per row ----------------
__global__ __launch_bounds__(256) void ln_kernel(
    const float* __restrict__ x, const float* __restrict__ gamma,
    const float* __restrict__ beta, float* __restrict__ xn)
{
    int row = blockIdx.x;
    int tid = threadIdx.x;
    const float2* xr = (const float2*)(x + (size_t)row * DMODEL);
    float2 v = xr[tid];
    float s  = v.x + v.y;
    float ss = v.x * v.x + v.y * v.y;
#pragma unroll
    for (int o = 32; o > 0; o >>= 1) {
        s  += __shfl_down(s, o, 64);
        ss += __shfl_down(ss, o, 64);
    }
    __shared__ float red[8];
    int wid = tid >> 6;
    if ((tid & 63) == 0) { red[wid * 2] = s; red[wid * 2 + 1] = ss; }
    __syncthreads();
    s  = red[0] + red[2] + red[4] + red[6];
    ss = red[1] + red[3] + red[5] + red[7];
    float mu  = s * (1.0f / (float)DMODEL);
    float var = ss * (1.0f / (float)DMODEL) - mu * mu;
    float inv = rsqrtf(var + 1e-5f);
    float2 g  = ((const float2*)gamma)[tid];
    float2 bb = ((const float2*)beta)[tid];
    float2 o2;
    o2.x = (v.x - mu) * inv * g.x + bb.x;
    o2.y = (v.y - mu) * inv * g.y + bb.y;
    ((float2*)(xn + (size_t)row * DMODEL))[tid] = o2;
}

// ---------------- Tiled fp32 NT-GEMM: C[M,N] = A[M,K] @ W[N,K]^T + bias ----------------
// MODE 0: write to (B,H,L,dk) layout (QKV); gridDim.z selects W0/W1/W2.
// MODE 1: write to (M,DMODEL) + residual add.
template<int MODE>
__global__ __launch_bounds__(256) void gemm_nt(
    const float* __restrict__ A,
    const float* __restrict__ W0, const float* __restrict__ W1, const float* __restrict__ W2,
    const float* __restrict__ b0, const float* __restrict__ b1, const float* __restrict__ b2,
    float* __restrict__ O0, float* __restrict__ O1, float* __restrict__ O2,
    const float* __restrict__ resid)
{
    const int K = DMODEL;
    const float* W; const float* bias; float* O;
    if (MODE == 0) {
        if (blockIdx.z == 0)      { W = W0; bias = b0; O = O0; }
        else if (blockIdx.z == 1) { W = W1; bias = b1; O = O1; }
        else                      { W = W2; bias = b2; O = O2; }
    } else { W = W0; bias = b0; O = O0; }

    // K-major LDS tiles (transposed) so compute reads are contiguous float4
    __shared__ float As[32][68];  // [kk][row], stride 68 floats (272B, 16B aligned)
    __shared__ float Bs[32][68];  // [kk][col]

    int tid = threadIdx.x;
    int m0 = blockIdx.y * 64, n0 = blockIdx.x * 64;
    int tx = tid & 15, ty = tid >> 4;

    float acc[4][4] = {};

    for (int k0 = 0; k0 < K; k0 += 32) {
#pragma unroll
        for (int rep = 0; rep < 2; ++rep) {
            int id  = tid + rep * 256;
            int row = id >> 3;          // 0..63
            int c4  = (id & 7) << 2;    // 0,4,...,28
            float4 a4 = *(const float4*)&A[(size_t)(m0 + row) * K + k0 + c4];
            As[c4 + 0][row] = a4.x; As[c4 + 1][row] = a4.y;
            As[c4 + 2][row] = a4.z; As[c4 + 3][row] = a4.w;
            float4 w4 = *(const float4*)&W[(size_t)(n0 + row) * K + k0 + c4];
            Bs[c4 + 0][row] = w4.x; Bs[c4 + 1][row] = w4.y;
            Bs[c4 + 2][row] = w4.z; Bs[c4 + 3][row] = w4.w;
        }
        __syncthreads();
#pragma unroll
        for (int kk = 0; kk < 32; ++kk) {
            float4 av = *(const float4*)&As[kk][ty * 4];
            float4 bv = *(const float4*)&Bs[kk][tx * 4];
            float ar[4] = {av.x, av.y, av.z, av.w};
            float br[4] = {bv.x, bv.y, bv.z, bv.w};
#pragma unroll
            for (int i = 0; i < 4; ++i)
#pragma unroll
                for (int j = 0; j < 4; ++j)
                    acc[i][j] = fmaf(ar[i], br[j], acc[i][j]);
        }
        __syncthreads();
    }

    float4 bias4 = *(const float4*)&bias[n0 + tx * 4];
#pragma unroll
    for (int i = 0; i < 4; ++i) {
        int m = m0 + ty * 4 + i;
        float4 r;
        r.x = acc[i][0] + bias4.x;
        r.y = acc[i][1] + bias4.y;
        r.z = acc[i][2] + bias4.z;
        r.w = acc[i][3] + bias4.w;
        if (MODE == 0) {
            int bb = m / LSEQ, ii = m % LSEQ;
            int h = blockIdx.x;  // N=512 -> 8 col-tiles = 8 heads
            *(float4*)&O[((size_t)((bb * NHEAD + h) * LSEQ + ii)) * DK + tx * 4] = r;
        } else {
            float4 res = *(const float4*)&resid[(size_t)m * DMODEL + n0 + tx * 4];
            r.x += res.x; r.y += res.y; r.z += res.z; r.w += res.w;
            *(float4*)&O[(size_t)m * DMODEL + n0 + tx * 4] = r;
        }
    }
}

// ---------------- Attention: one block per (b,h,i) query row ----------------
__global__ __launch_bounds__(256) void attn_kernel(
    const float* __restrict__ q, const float* __restrict__ k,
    const float* __restrict__ v, const float* __restrict__ E,
    float* __restrict__ ctx)
{
    int i = blockIdx.x, h = blockIdx.y, b = blockIdx.z;
    int tid = threadIdx.x;
    size_t base = (size_t)(b * NHEAD + h) * LSEQ * DK;

    __shared__ float qs[DK];
    __shared__ float sbuf[LSEQ];
    __shared__ float red[4];
    __shared__ float pvred[4][DK];

    if (tid < 16)
        ((float4*)qs)[tid] = ((const float4*)(q + base + (size_t)i * DK))[tid];
    __syncthreads();

    // scores: s[j] = (q.K_j)/8 + q.E_{j-i+L-1}
    for (int j = tid; j < LSEQ; j += 256) {
        const float4* krow = (const float4*)(k + base + (size_t)j * DK);
        const float4* erow = (const float4*)(E + (size_t)(j - i + LSEQ - 1) * DK);
        float dq = 0.f, de = 0.f;
#pragma unroll
        for (int c = 0; c < 16; ++c) {
            float4 q4 = ((const float4*)qs)[c];
            float4 k4 = krow[c];
            float4 e4 = erow[c];
            dq = fmaf(q4.x, k4.x, fmaf(q4.y, k4.y, fmaf(q4.z, k4.z, fmaf(q4.w, k4.w, dq))));
            de = fmaf(q4.x, e4.x, fmaf(q4.y, e4.y, fmaf(q4.z, e4.z, fmaf(q4.w, e4.w, de))));
        }
        sbuf[j] = dq * 0.125f + de;
    }
    __syncthreads();

    // row max
    float m = -1e30f;
    for (int j = tid; j < LSEQ; j += 256) m = fmaxf(m, sbuf[j]);
#pragma unroll
    for (int o = 32; o > 0; o >>= 1) m = fmaxf(m, __shfl_down(m, o, 64));
    if ((tid & 63) == 0) red[tid >> 6] = m;
    __syncthreads();
    m = fmaxf(fmaxf(red[0], red[1]), fmaxf(red[2], red[3]));

    // exp + sum
    float s = 0.f;
    for (int j = tid; j < LSEQ; j += 256) {
        float e = __expf(sbuf[j] - m);
        sbuf[j] = e;
        s += e;
    }
#pragma unroll
    for (int o = 32; o > 0; o >>= 1) s += __shfl_down(s, o, 64);
    __syncthreads();  // all reads of red (max) done before reuse
    if ((tid & 63) == 0) red[tid >> 6] = s;
    __syncthreads();
    float total = red[0] + red[1] + red[2] + red[3];

    // PV: wave w handles j in [w*250, (w+1)*250), lane d = tid&63
    int d = tid & 63, chunk = tid >> 6;
    float acc = 0.f;
    const float* vp = v + base + d;
    for (int j = chunk * 250; j < (chunk + 1) * 250; ++j)
        acc = fmaf(sbuf[j], vp[(size_t)j * DK], acc);
    pvred[chunk][d] = acc;
    __syncthreads();
    if (tid < DK) {
        float r = (pvred[0][tid] + pvred[1][tid] + pvred[2][tid] + pvred[3][tid]) / total;
        ctx[((size_t)(b * LSEQ + i)) * DMODEL + h * DK + tid] = r;
    }
}

extern "C" void kernel_launch(void* const* d_in, const int* in_sizes, int n_in,
                              void* d_out, int out_size, void* d_ws, size_t ws_size,
                              hipStream_t stream)
{
    const float* x     = (const float*)d_in[0];
    const float* Wq    = (const float*)d_in[1];
    const float* bq    = (const float*)d_in[2];
    const float* Wk    = (const float*)d_in[3];
    const float* bk    = (const float*)d_in[4];
    const float* Wv    = (const float*)d_in[5];
    const float* bv    = (const float*)d_in[6];
    const float* Wo    = (const float*)d_in[7];
    const float* bo    = (const float*)d_in[8];
    const float* E     = (const float*)d_in[9];
    const float* gamma = (const float*)d_in[10];
    const float* beta  = (const float*)d_in[11];
    float* out = (float*)d_out;

    const int B = 8;
    const size_t nBLD = (size_t)B * LSEQ * DMODEL;  // 4,096,000 floats
    float* xn  = (float*)d_ws;       // 16 MB, reused as ctx after QKV
    float* qb  = xn + nBLD;
    float* kb  = qb + nBLD;
    float* vb  = kb + nBLD;
    float* ctx = xn;                 // alias: xn dead after QKV GEMM

    const int M = B * LSEQ;  // 8000, divisible by 64

    ln_kernel<<<M, 256, 0, stream>>>(x, gamma, beta, xn);
    gemm_nt<0><<<dim3(DMODEL / 64, M / 64, 3), 256, 0, stream>>>(
        xn, Wq, Wk, Wv, bq, bk, bv, qb, kb, vb, nullptr);
    attn_kernel<<<dim3(LSEQ, NHEAD, B), 256, 0, stream>>>(qb, kb, vb, E, ctx);
    gemm_nt<1><<<dim3(DMODEL / 64, M / 64, 1), 256, 0, stream>>>(
        ctx, Wo, nullptr, nullptr, bo, nullptr, nullptr, out, nullptr, nullptr, x);
}

// Round 2
// 474.630 us; speedup vs baseline: 10.0452x; 10.0452x over previous
//
#include <hip/hip_runtime.h>
#include <hip/hip_bf16.h>

#define NHEAD 8
#define DK 64
#define DMODEL 512
#define LSEQ 1000
#define TI 64
#define TJ 64
#define NJT 16   // ceil(1000/64)

typedef __attribute__((ext_vector_type(8))) short bf16x8;
typedef __attribute__((ext_vector_type(4))) float f32x4;

__device__ inline short f2bf(float f) {
    __hip_bfloat16 h = __float2bfloat16(f);
    return *reinterpret_cast<short*>(&h);
}
__device__ inline float bf2f(short s) {
    unsigned int u = ((unsigned int)(unsigned short)s) << 16;
    return __uint_as_float(u);
}

// ---------------- LayerNorm: one block per row ----------------
__global__ __launch_bounds__(256) void ln_kernel(
    const float* __restrict__ x, const float* __restrict__ gamma,
    const float* __restrict__ beta, float* __restrict__ xn)
{
    int row = blockIdx.x;
    int tid = threadIdx.x;
    const float2* xr = (const float2*)(x + (size_t)row * DMODEL);
    float2 v = xr[tid];
    float s  = v.x + v.y;
    float ss = v.x * v.x + v.y * v.y;
#pragma unroll
    for (int o = 32; o > 0; o >>= 1) {
        s  += __shfl_down(s, o, 64);
        ss += __shfl_down(ss, o, 64);
    }
    __shared__ float red[8];
    int wid = tid >> 6;
    if ((tid & 63) == 0) { red[wid * 2] = s; red[wid * 2 + 1] = ss; }
    __syncthreads();
    s  = red[0] + red[2] + red[4] + red[6];
    ss = red[1] + red[3] + red[5] + red[7];
    float mu  = s * (1.0f / (float)DMODEL);
    float var = ss * (1.0f / (float)DMODEL) - mu * mu;
    float inv = rsqrtf(var + 1e-5f);
    float2 g  = ((const float2*)gamma)[tid];
    float2 bb = ((const float2*)beta)[tid];
    float2 o2;
    o2.x = (v.x - mu) * inv * g.x + bb.x;
    o2.y = (v.y - mu) * inv * g.y + bb.y;
    ((float2*)(xn + (size_t)row * DMODEL))[tid] = o2;
}

// ---------------- Tiled fp32 NT-GEMM (unchanged this round) ----------------
template<int MODE>
__global__ __launch_bounds__(256) void gemm_nt(
    const float* __restrict__ A,
    const float* __restrict__ W0, const float* __restrict__ W1, const float* __restrict__ W2,
    const float* __restrict__ b0, const float* __restrict__ b1, const float* __restrict__ b2,
    float* __restrict__ O0, float* __restrict__ O1, float* __restrict__ O2,
    const float* __restrict__ resid)
{
    const int K = DMODEL;
    const float* W; const float* bias; float* O;
    if (MODE == 0) {
        if (blockIdx.z == 0)      { W = W0; bias = b0; O = O0; }
        else if (blockIdx.z == 1) { W = W1; bias = b1; O = O1; }
        else                      { W = W2; bias = b2; O = O2; }
    } else { W = W0; bias = b0; O = O0; }

    __shared__ float As[32][68];
    __shared__ float Bs[32][68];

    int tid = threadIdx.x;
    int m0 = blockIdx.y * 64, n0 = blockIdx.x * 64;
    int tx = tid & 15, ty = tid >> 4;

    float acc[4][4] = {};

    for (int k0 = 0; k0 < K; k0 += 32) {
#pragma unroll
        for (int rep = 0; rep < 2; ++rep) {
            int id  = tid + rep * 256;
            int row = id >> 3;
            int c4  = (id & 7) << 2;
            float4 a4 = *(const float4*)&A[(size_t)(m0 + row) * K + k0 + c4];
            As[c4 + 0][row] = a4.x; As[c4 + 1][row] = a4.y;
            As[c4 + 2][row] = a4.z; As[c4 + 3][row] = a4.w;
            float4 w4 = *(const float4*)&W[(size_t)(n0 + row) * K + k0 + c4];
            Bs[c4 + 0][row] = w4.x; Bs[c4 + 1][row] = w4.y;
            Bs[c4 + 2][row] = w4.z; Bs[c4 + 3][row] = w4.w;
        }
        __syncthreads();
#pragma unroll
        for (int kk = 0; kk < 32; ++kk) {
            float4 av = *(const float4*)&As[kk][ty * 4];
            float4 bv = *(const float4*)&Bs[kk][tx * 4];
            float ar[4] = {av.x, av.y, av.z, av.w};
            float br[4] = {bv.x, bv.y, bv.z, bv.w};
#pragma unroll
            for (int i = 0; i < 4; ++i)
#pragma unroll
                for (int j = 0; j < 4; ++j)
                    acc[i][j] = fmaf(ar[i], br[j], acc[i][j]);
        }
        __syncthreads();
    }

    float4 bias4 = *(const float4*)&bias[n0 + tx * 4];
#pragma unroll
    for (int i = 0; i < 4; ++i) {
        int m = m0 + ty * 4 + i;
        float4 r;
        r.x = acc[i][0] + bias4.x;
        r.y = acc[i][1] + bias4.y;
        r.z = acc[i][2] + bias4.z;
        r.w = acc[i][3] + bias4.w;
        if (MODE == 0) {
            int bb = m / LSEQ, ii = m % LSEQ;
            int h = blockIdx.x;
            *(float4*)&O[((size_t)((bb * NHEAD + h) * LSEQ + ii)) * DK + tx * 4] = r;
        } else {
            float4 res = *(const float4*)&resid[(size_t)m * DMODEL + n0 + tx * 4];
            r.x += res.x; r.y += res.y; r.z += res.z; r.w += res.w;
            *(float4*)&O[(size_t)m * DMODEL + n0 + tx * 4] = r;
        }
    }
}

// ---------------- Flash attention, bf16 MFMA ----------------
// Block = (i-tile, h, b); 4 waves; wave w owns query rows [w*16, w*16+16).
// Scores: S = (Q/8)·K^T + (Q/8)·(8E)^T  -> shared A fragments.
__global__ __launch_bounds__(256, 2) void attn_mfma(
    const float* __restrict__ q, const float* __restrict__ k,
    const float* __restrict__ v, const float* __restrict__ E,
    float* __restrict__ ctx)
{
    __shared__ short Qs[TI][72];     // Q/8, bf16
    __shared__ short Kt[TJ][72];     // K tile, bf16
    __shared__ short Et[128][72];    // 8*E delta-window, bf16
    __shared__ short Vt[DK][72];     // V tile TRANSPOSED: Vt[d][j]
    __shared__ short Pp[TI][136];    // pos-score tile (bf16), wave-private rows
    __shared__ short Pl[TI][72];     // probabilities (bf16), wave-private rows

    const int it = blockIdx.x, h = blockIdx.y, b = blockIdx.z;
    const int i0 = it * TI;
    const int tid = threadIdx.x;
    const int lane = tid & 63, w = tid >> 6;
    const int g = lane >> 4, c = lane & 15;

    const size_t base = (size_t)(b * NHEAD + h) * LSEQ * DK;

    // ---- stage Qs = Q/8 (row-clamped) ----
#pragma unroll
    for (int rep = 0; rep < 2; ++rep) {
        int id = tid + rep * 256;           // 512 units: 64 rows x 8 chunks
        int row = id >> 3, c0 = (id & 7) * 8;
        int gr = i0 + row; if (gr > LSEQ - 1) gr = LSEQ - 1;
        const float* src = q + base + (size_t)gr * DK + c0;
        float4 x0 = *(const float4*)src, x1 = *(const float4*)(src + 4);
        short t[8] = { f2bf(x0.x * 0.125f), f2bf(x0.y * 0.125f),
                       f2bf(x0.z * 0.125f), f2bf(x0.w * 0.125f),
                       f2bf(x1.x * 0.125f), f2bf(x1.y * 0.125f),
                       f2bf(x1.z * 0.125f), f2bf(x1.w * 0.125f) };
        *(int4*)&Qs[row][c0] = *(int4*)t;
    }
    __syncthreads();

    // A fragments (Q) — constant across j-tiles
    bf16x8 Aq0 = *(bf16x8*)&Qs[w * 16 + c][g * 8];
    bf16x8 Aq1 = *(bf16x8*)&Qs[w * 16 + c][32 + g * 8];

    float mrow[4], lrow[4];
    f32x4 acc[4];
#pragma unroll
    for (int r = 0; r < 4; ++r) { mrow[r] = -1e30f; lrow[r] = 0.f; }
#pragma unroll
    for (int fd = 0; fd < 4; ++fd) acc[fd] = (f32x4){0.f, 0.f, 0.f, 0.f};

    for (int jt = 0; jt < NJT; ++jt) {
        const int j0 = jt * TJ;
        const int d0 = j0 - i0 + (LSEQ - 1) - 63;   // delta window start
        __syncthreads();   // prev iteration's LDS reads complete

        // ---- stage K tile ----
#pragma unroll
        for (int rep = 0; rep < 2; ++rep) {
            int id = tid + rep * 256;
            int row = id >> 3, c0 = (id & 7) * 8;
            int gr = j0 + row; if (gr > LSEQ - 1) gr = LSEQ - 1;
            const float* src = k + base + (size_t)gr * DK + c0;
            float4 x0 = *(const float4*)src, x1 = *(const float4*)(src + 4);
            short t[8] = { f2bf(x0.x), f2bf(x0.y), f2bf(x0.z), f2bf(x0.w),
                           f2bf(x1.x), f2bf(x1.y), f2bf(x1.z), f2bf(x1.w) };
            *(int4*)&Kt[row][c0] = *(int4*)t;
        }
        // ---- stage 8*E delta window (128 rows, clamped) ----
#pragma unroll
        for (int rep = 0; rep < 4; ++rep) {
            int id = tid + rep * 256;
            int row = id >> 3, c0 = (id & 7) * 8;
            int dd = d0 + row;
            if (dd < 0) dd = 0;
            if (dd > 2 * LSEQ - 2) dd = 2 * LSEQ - 2;
            const float* src = E + (size_t)dd * DK + c0;
            float4 x0 = *(const float4*)src, x1 = *(const float4*)(src + 4);
            short t[8] = { f2bf(x0.x * 8.f), f2bf(x0.y * 8.f),
                           f2bf(x0.z * 8.f), f2bf(x0.w * 8.f),
                           f2bf(x1.x * 8.f), f2bf(x1.y * 8.f),
                           f2bf(x1.z * 8.f), f2bf(x1.w * 8.f) };
            *(int4*)&Et[row][c0] = *(int4*)t;
        }
        // ---- stage V tile transposed: Vt[d][j] ----
#pragma unroll
        for (int rep = 0; rep < 4; ++rep) {
            int id = tid + rep * 256;       // 1024 units: 64 j x 16 d-quads
            int j = id >> 4, dd0 = (id & 15) * 4;
            int gr = j0 + j; if (gr > LSEQ - 1) gr = LSEQ - 1;
            float4 x0 = *(const float4*)(v + base + (size_t)gr * DK + dd0);
            Vt[dd0 + 0][j] = f2bf(x0.x);
            Vt[dd0 + 1][j] = f2bf(x0.y);
            Vt[dd0 + 2][j] = f2bf(x0.z);
            Vt[dd0 + 3][j] = f2bf(x0.w);
        }
        __syncthreads();

        // ---- pos scores: Ppos = Aq @ Et^T (wave-private rows of Pp) ----
#pragma unroll
        for (int fd = 0; fd < 8; ++fd) {
            f32x4 pa = (f32x4){0.f, 0.f, 0.f, 0.f};
            bf16x8 b0 = *(bf16x8*)&Et[fd * 16 + c][g * 8];
            bf16x8 b1 = *(bf16x8*)&Et[fd * 16 + c][32 + g * 8];
            pa = __builtin_amdgcn_mfma_f32_16x16x32_bf16(Aq0, b0, pa, 0, 0, 0);
            pa = __builtin_amdgcn_mfma_f32_16x16x32_bf16(Aq1, b1, pa, 0, 0, 0);
#pragma unroll
            for (int r = 0; r < 4; ++r)
                Pp[w * 16 + g * 4 + r][fd * 16 + c] = f2bf(pa[r]);
        }

        // ---- QK^T ----
        f32x4 sf[4];
#pragma unroll
        for (int fj = 0; fj < 4; ++fj) {
            f32x4 s4 = (f32x4){0.f, 0.f, 0.f, 0.f};
            bf16x8 b0 = *(bf16x8*)&Kt[fj * 16 + c][g * 8];
            bf16x8 b1 = *(bf16x8*)&Kt[fj * 16 + c][32 + g * 8];
            s4 = __builtin_amdgcn_mfma_f32_16x16x32_bf16(Aq0, b0, s4, 0, 0, 0);
            s4 = __builtin_amdgcn_mfma_f32_16x16x32_bf16(Aq1, b1, s4, 0, 0, 0);
            sf[fj] = s4;
        }

        // ---- add pos (diagonal gather), mask, online softmax ----
        float sv[4][4], pm[4];
#pragma unroll
        for (int r = 0; r < 4; ++r) pm[r] = -1e30f;
#pragma unroll
        for (int fj = 0; fj < 4; ++fj) {
            int jl = fj * 16 + c;
            bool valid = (j0 + jl) < LSEQ;
#pragma unroll
            for (int r = 0; r < 4; ++r) {
                int ilt = w * 16 + g * 4 + r;
                int d = jl - ilt + 63;      // in [0,126] over tile extents
                // ilt in [w*16, w*16+16) so d in [jl-63+63-?..]; clamp not needed:
                // jl in [0,64), ilt in [0,64) -> d in [0,126] only when |jl-ilt|<=63;
                // within a 64x64 tile always true.
                float x = sf[fj][r] + bf2f(Pp[ilt][d]);
                if (!valid) x = -1e30f;
                sv[fj][r] = x;
                pm[r] = fmaxf(pm[r], x);
            }
        }
#pragma unroll
        for (int r = 0; r < 4; ++r) {
            float vv = pm[r];
            vv = fmaxf(vv, __shfl_xor(vv, 1));
            vv = fmaxf(vv, __shfl_xor(vv, 2));
            vv = fmaxf(vv, __shfl_xor(vv, 4));
            vv = fmaxf(vv, __shfl_xor(vv, 8));
            pm[r] = vv;
        }
        float psum[4];
#pragma unroll
        for (int r = 0; r < 4; ++r) {
            float mn = fmaxf(mrow[r], pm[r]);
            float sc = __expf(mrow[r] - mn);
            mrow[r] = mn;
            lrow[r] *= sc;
#pragma unroll
            for (int fd = 0; fd < 4; ++fd) {
                acc[fd][r] *= sc;
            }
            psum[r] = 0.f;
        }
#pragma unroll
        for (int fj = 0; fj < 4; ++fj) {
            int jl = fj * 16 + c;
#pragma unroll
            for (int r = 0; r < 4; ++r) {
                float p = __expf(sv[fj][r] - mrow[r]);
                psum[r] += p;
                Pl[w * 16 + g * 4 + r][jl] = f2bf(p);
            }
        }
#pragma unroll
        for (int r = 0; r < 4; ++r) {
            float vv = psum[r];
            vv += __shfl_xor(vv, 1);
            vv += __shfl_xor(vv, 2);
            vv += __shfl_xor(vv, 4);
            vv += __shfl_xor(vv, 8);
            lrow[r] += vv;
        }

        // ---- PV: acc += P @ V   (Pl rows wave-private; Vt staged pre-barrier) ----
#pragma unroll
        for (int ks = 0; ks < 2; ++ks) {
            bf16x8 ap = *(bf16x8*)&Pl[w * 16 + c][ks * 32 + g * 8];
#pragma unroll
            for (int fd = 0; fd < 4; ++fd) {
                bf16x8 bv2 = *(bf16x8*)&Vt[fd * 16 + c][ks * 32 + g * 8];
                acc[fd] = __builtin_amdgcn_mfma_f32_16x16x32_bf16(ap, bv2, acc[fd], 0, 0, 0);
            }
        }
    }

    // ---- epilogue: normalize + store ctx in (B, L, D) layout ----
#pragma unroll
    for (int r = 0; r < 4; ++r) {
        int ig = i0 + w * 16 + g * 4 + r;
        if (ig < LSEQ) {
            float inv = 1.0f / lrow[r];
#pragma unroll
            for (int fd = 0; fd < 4; ++fd) {
                ctx[((size_t)(b * LSEQ + ig)) * DMODEL + h * DK + fd * 16 + c] =
                    acc[fd][r] * inv;
            }
        }
    }
}

extern "C" void kernel_launch(void* const* d_in, const int* in_sizes, int n_in,
                              void* d_out, int out_size, void* d_ws, size_t ws_size,
                              hipStream_t stream)
{
    const float* x     = (const float*)d_in[0];
    const float* Wq    = (const float*)d_in[1];
    const float* bq    = (const float*)d_in[2];
    const float* Wk    = (const float*)d_in[3];
    const float* bk    = (const float*)d_in[4];
    const float* Wv    = (const float*)d_in[5];
    const float* bv    = (const float*)d_in[6];
    const float* Wo    = (const float*)d_in[7];
    const float* bo    = (const float*)d_in[8];
    const float* E     = (const float*)d_in[9];
    const float* gamma = (const float*)d_in[10];
    const float* beta  = (const float*)d_in[11];
    float* out = (float*)d_out;

    const int B = 8;
    const size_t nBLD = (size_t)B * LSEQ * DMODEL;
    float* xn  = (float*)d_ws;
    float* qb  = xn + nBLD;
    float* kb  = qb + nBLD;
    float* vb  = kb + nBLD;
    float* ctx = xn;   // alias: xn dead after QKV GEMM

    const int M = B * LSEQ;  // 8000

    ln_kernel<<<M, 256, 0, stream>>>(x, gamma, beta, xn);
    gemm_nt<0><<<dim3(DMODEL / 64, M / 64, 3), 256, 0, stream>>>(
        xn, Wq, Wk, Wv, bq, bk, bv, qb, kb, vb, nullptr);
    attn_mfma<<<dim3((LSEQ + TI - 1) / TI, NHEAD, B), 256, 0, stream>>>(
        qb, kb, vb, E, ctx);
    gemm_nt<1><<<dim3(DMODEL / 64, M / 64, 1), 256, 0, stream>>>(
        ctx, Wo, nullptr, nullptr, bo, nullptr, nullptr, out, nullptr, nullptr, x);
}

// Round 5
// 286.680 us; speedup vs baseline: 16.6309x; 1.6556x over previous
//
#include <hip/hip_runtime.h>
#include <hip/hip_bf16.h>

#define NHEAD 8
#define DK 64
#define DMODEL 512
#define LSEQ 1000
#define TI 64
#define TJ 64
#define NJT 16

typedef __attribute__((ext_vector_type(8))) short bf16x8;
typedef __attribute__((ext_vector_type(4))) float f32x4;

__device__ inline short f2bf(float f) {
    __hip_bfloat16 h = __float2bfloat16(f);
    return *reinterpret_cast<short*>(&h);
}
__device__ inline float bf2f(short s) {
    unsigned int u = ((unsigned int)(unsigned short)s) << 16;
    return __uint_as_float(u);
}
__device__ inline void gload_lds16(const void* g, void* l) {
    __builtin_amdgcn_global_load_lds(
        (const __attribute__((address_space(1))) unsigned int*)g,
        (__attribute__((address_space(3))) unsigned int*)l, 16, 0, 0);
}

// ---------------- convert weights/E to bf16 (Wq,bq folded /8; E folded x8) ----------------
// regions (in 4-elem quads): Wqkv 196608 | Wo 65536 | E 31984  => 294128 quads
__global__ __launch_bounds__(256) void convert_kernel(
    const float* __restrict__ Wq, const float* __restrict__ Wk, const float* __restrict__ Wv,
    const float* __restrict__ Wo, const float* __restrict__ E,
    short* __restrict__ Wqkv_bf, short* __restrict__ Wo_bf, short* __restrict__ E_bf)
{
    int qd = blockIdx.x * 256 + threadIdx.x;
    if (qd < 196608) {
        int flat = qd * 4;
        int row = flat >> 9, col = flat & 511;
        int proj = row >> 9, rrow = row & 511;
        const float* src = proj == 0 ? Wq : (proj == 1 ? Wk : Wv);
        float sc = proj == 0 ? 0.125f : 1.0f;
        float4 x = *(const float4*)&src[(size_t)rrow * 512 + col];
        short t[4] = { f2bf(x.x * sc), f2bf(x.y * sc), f2bf(x.z * sc), f2bf(x.w * sc) };
        *(uint2*)&Wqkv_bf[flat] = *(uint2*)t;
    } else if (qd < 262144) {
        int flat = (qd - 196608) * 4;
        float4 x = *(const float4*)&Wo[flat];
        short t[4] = { f2bf(x.x), f2bf(x.y), f2bf(x.z), f2bf(x.w) };
        *(uint2*)&Wo_bf[flat] = *(uint2*)t;
    } else if (qd < 294128) {
        int flat = (qd - 262144) * 4;
        float4 x = *(const float4*)&E[flat];
        short t[4] = { f2bf(x.x * 8.f), f2bf(x.y * 8.f), f2bf(x.z * 8.f), f2bf(x.w * 8.f) };
        *(uint2*)&E_bf[flat] = *(uint2*)t;
    }
}

// ---------------- LayerNorm -> bf16 ----------------
__global__ __launch_bounds__(256) void ln_kernel(
    const float* __restrict__ x, const float* __restrict__ gamma,
    const float* __restrict__ beta, short* __restrict__ xn)
{
    int row = blockIdx.x;
    int tid = threadIdx.x;
    const float2* xr = (const float2*)(x + (size_t)row * DMODEL);
    float2 v = xr[tid];
    float s  = v.x + v.y;
    float ss = v.x * v.x + v.y * v.y;
#pragma unroll
    for (int o = 32; o > 0; o >>= 1) {
        s  += __shfl_down(s, o, 64);
        ss += __shfl_down(ss, o, 64);
    }
    __shared__ float red[8];
    int wid = tid >> 6;
    if ((tid & 63) == 0) { red[wid * 2] = s; red[wid * 2 + 1] = ss; }
    __syncthreads();
    s  = red[0] + red[2] + red[4] + red[6];
    ss = red[1] + red[3] + red[5] + red[7];
    float mu  = s * (1.0f / (float)DMODEL);
    float var = ss * (1.0f / (float)DMODEL) - mu * mu;
    float inv = rsqrtf(var + 1e-5f);
    float2 g  = ((const float2*)gamma)[tid];
    float2 bb = ((const float2*)beta)[tid];
    short o2[2];
    o2[0] = f2bf((v.x - mu) * inv * g.x + bb.x);
    o2[1] = f2bf((v.y - mu) * inv * g.y + bb.y);
    *(unsigned int*)&xn[(size_t)row * DMODEL + tid * 2] = *(unsigned int*)o2;
}

// ---------------- bf16 MFMA GEMM (m97 structure: 128x128 tile, BK=32) ----------------
// C[M,N] = A[M,512](bf16) @ W[N,512]^T(bf16) + bias
// MODE 0: N=1536 fused QKV -> write bf16 (B,H,L,dk); Wq/bq pre-scaled by 1/8.
// MODE 1: N=512 -> fp32 out + bias + residual.
template<int MODE>
__global__ __launch_bounds__(256) void gemm_bf16(
    const short* __restrict__ A, const short* __restrict__ W,
    const float* __restrict__ b0, const float* __restrict__ b1, const float* __restrict__ b2,
    short* __restrict__ Oq, short* __restrict__ Ok, short* __restrict__ Ov,
    float* __restrict__ Of, const float* __restrict__ resid)
{
    __shared__ short As[128 * 32];
    __shared__ short Bs[128 * 32];
    const int K = 512;
    const int tid = threadIdx.x;
    const int lane = tid & 63, w = tid >> 6;
    const int m0 = blockIdx.y * 128, n0 = blockIdx.x * 128;
    const int wr = w >> 1, wc = w & 1;

    // staging map: wave w stages chunks {2w, 2w+1}; chunk ch = rows [ch*16, ch*16+16)
    // lane l -> row ch*16 + l/4, col shorts (l&3)*8 (16B)
    const int srow = (lane >> 2);
    const int scol = (lane & 3) * 8;
    int ga0 = m0 + (w * 2 + 0) * 16 + srow; if (ga0 > 7999) ga0 = 7999;
    int ga1 = m0 + (w * 2 + 1) * 16 + srow; if (ga1 > 7999) ga1 = 7999;
    const int gb0 = n0 + (w * 2 + 0) * 16 + srow;
    const int gb1 = n0 + (w * 2 + 1) * 16 + srow;

    f32x4 acc[4][4];
#pragma unroll
    for (int i = 0; i < 4; ++i)
#pragma unroll
        for (int j = 0; j < 4; ++j) acc[i][j] = (f32x4){0.f, 0.f, 0.f, 0.f};

    for (int k0 = 0; k0 < K; k0 += 32) {
        __syncthreads();
        gload_lds16(&A[(size_t)ga0 * K + k0 + scol], &As[(w * 2 + 0) * 512]);
        gload_lds16(&A[(size_t)ga1 * K + k0 + scol], &As[(w * 2 + 1) * 512]);
        gload_lds16(&W[(size_t)gb0 * K + k0 + scol], &Bs[(w * 2 + 0) * 512]);
        gload_lds16(&W[(size_t)gb1 * K + k0 + scol], &Bs[(w * 2 + 1) * 512]);
        __syncthreads();

        bf16x8 af[4], bf[4];
#pragma unroll
        for (int fi = 0; fi < 4; ++fi)
            af[fi] = *(bf16x8*)&As[(wr * 64 + fi * 16 + (lane & 15)) * 32 + (lane >> 4) * 8];
#pragma unroll
        for (int fj = 0; fj < 4; ++fj)
            bf[fj] = *(bf16x8*)&Bs[(wc * 64 + fj * 16 + (lane & 15)) * 32 + (lane >> 4) * 8];
#pragma unroll
        for (int fi = 0; fi < 4; ++fi)
#pragma unroll
            for (int fj = 0; fj < 4; ++fj)
                acc[fi][fj] = __builtin_amdgcn_mfma_f32_16x16x32_bf16(af[fi], bf[fj], acc[fi][fj], 0, 0, 0);
    }

#pragma unroll
    for (int fi = 0; fi < 4; ++fi) {
#pragma unroll
        for (int fj = 0; fj < 4; ++fj) {
#pragma unroll
            for (int r = 0; r < 4; ++r) {
                int m = m0 + wr * 64 + fi * 16 + (lane >> 4) * 4 + r;
                if (m >= 8000) continue;
                int n = n0 + wc * 64 + fj * 16 + (lane & 15);
                float val = acc[fi][fj][r];
                if (MODE == 0) {
                    int proj = n >> 9, rem = n & 511;
                    int h = rem >> 6, d = rem & 63;
                    float bias = proj == 0 ? b0[rem] * 0.125f : (proj == 1 ? b1[rem] : b2[rem]);
                    short* O = proj == 0 ? Oq : (proj == 1 ? Ok : Ov);
                    int bb = m / 1000, ii = m - bb * 1000;
                    O[((size_t)(bb * NHEAD + h) * LSEQ + ii) * DK + d] = f2bf(val + bias);
                } else {
                    Of[(size_t)m * DMODEL + n] = val + b0[n] + resid[(size_t)m * DMODEL + n];
                }
            }
        }
    }
}

// ---------------- Flash attention, bf16 MFMA, bf16 I/O ----------------
// q = Q/8 (pre-folded), E = 8*rel_pos (pre-folded). ctx written bf16 (B,L,D).
__global__ __launch_bounds__(256, 2) void attn_mfma(
    const short* __restrict__ q, const short* __restrict__ k,
    const short* __restrict__ v, const short* __restrict__ E,
    short* __restrict__ ctx)
{
    __shared__ short Qs[TI][72];
    __shared__ short Kt[TJ][72];
    __shared__ short Et[128][72];
    __shared__ short Vt[DK][72];
    __shared__ short Pp[TI][136];
    __shared__ short Pl[TI][72];

    const int it = blockIdx.x, h = blockIdx.y, b = blockIdx.z;
    const int i0 = it * TI;
    const int tid = threadIdx.x;
    const int lane = tid & 63, w = tid >> 6;
    const int g = lane >> 4, c = lane & 15;

    const size_t base = (size_t)(b * NHEAD + h) * LSEQ * DK;

    // stage Q tile (bf16 direct copy, row-clamped)
#pragma unroll
    for (int rep = 0; rep < 2; ++rep) {
        int id = tid + rep * 256;
        int row = id >> 3, c0 = (id & 7) * 8;
        int gr = i0 + row; if (gr > LSEQ - 1) gr = LSEQ - 1;
        *(int4*)&Qs[row][c0] = *(const int4*)&q[base + (size_t)gr * DK + c0];
    }
    __syncthreads();

    bf16x8 Aq0 = *(bf16x8*)&Qs[w * 16 + c][g * 8];
    bf16x8 Aq1 = *(bf16x8*)&Qs[w * 16 + c][32 + g * 8];

    float mrow[4], lrow[4];
    f32x4 acc[4];
#pragma unroll
    for (int r = 0; r < 4; ++r) { mrow[r] = -1e30f; lrow[r] = 0.f; }
#pragma unroll
    for (int fd = 0; fd < 4; ++fd) acc[fd] = (f32x4){0.f, 0.f, 0.f, 0.f};

    for (int jt = 0; jt < NJT; ++jt) {
        const int j0 = jt * TJ;
        const int d0 = j0 - i0 + (LSEQ - 1) - 63;
        __syncthreads();

        // K tile
#pragma unroll
        for (int rep = 0; rep < 2; ++rep) {
            int id = tid + rep * 256;
            int row = id >> 3, c0 = (id & 7) * 8;
            int gr = j0 + row; if (gr > LSEQ - 1) gr = LSEQ - 1;
            *(int4*)&Kt[row][c0] = *(const int4*)&k[base + (size_t)gr * DK + c0];
        }
        // E window (128 rows, clamped)
#pragma unroll
        for (int rep = 0; rep < 4; ++rep) {
            int id = tid + rep * 256;
            int row = id >> 3, c0 = (id & 7) * 8;
            int dd = d0 + row;
            if (dd < 0) dd = 0;
            if (dd > 2 * LSEQ - 2) dd = 2 * LSEQ - 2;
            *(int4*)&Et[row][c0] = *(const int4*)&E[(size_t)dd * DK + c0];
        }
        // V tile transposed
#pragma unroll
        for (int rep = 0; rep < 4; ++rep) {
            int id = tid + rep * 256;
            int j = id >> 4, dq = (id & 15) * 4;
            int gr = j0 + j; if (gr > LSEQ - 1) gr = LSEQ - 1;
            short t[4];
            *(int2*)t = *(const int2*)&v[base + (size_t)gr * DK + dq];
            Vt[dq + 0][j] = t[0];
            Vt[dq + 1][j] = t[1];
            Vt[dq + 2][j] = t[2];
            Vt[dq + 3][j] = t[3];
        }
        __syncthreads();

        // pos scores: Pp = Aq @ Et^T (wave-private rows)
#pragma unroll
        for (int fd = 0; fd < 8; ++fd) {
            f32x4 pa = (f32x4){0.f, 0.f, 0.f, 0.f};
            bf16x8 e0 = *(bf16x8*)&Et[fd * 16 + c][g * 8];
            bf16x8 e1 = *(bf16x8*)&Et[fd * 16 + c][32 + g * 8];
            pa = __builtin_amdgcn_mfma_f32_16x16x32_bf16(Aq0, e0, pa, 0, 0, 0);
            pa = __builtin_amdgcn_mfma_f32_16x16x32_bf16(Aq1, e1, pa, 0, 0, 0);
#pragma unroll
            for (int r = 0; r < 4; ++r)
                Pp[w * 16 + g * 4 + r][fd * 16 + c] = f2bf(pa[r]);
        }

        // QK^T
        f32x4 sf[4];
#pragma unroll
        for (int fj = 0; fj < 4; ++fj) {
            f32x4 s4 = (f32x4){0.f, 0.f, 0.f, 0.f};
            bf16x8 k0v = *(bf16x8*)&Kt[fj * 16 + c][g * 8];
            bf16x8 k1v = *(bf16x8*)&Kt[fj * 16 + c][32 + g * 8];
            s4 = __builtin_amdgcn_mfma_f32_16x16x32_bf16(Aq0, k0v, s4, 0, 0, 0);
            s4 = __builtin_amdgcn_mfma_f32_16x16x32_bf16(Aq1, k1v, s4, 0, 0, 0);
            sf[fj] = s4;
        }

        // add pos (diag gather), mask, online softmax
        float sv[4][4], pm[4];
#pragma unroll
        for (int r = 0; r < 4; ++r) pm[r] = -1e30f;
#pragma unroll
        for (int fj = 0; fj < 4; ++fj) {
            int jl = fj * 16 + c;
            bool valid = (j0 + jl) < LSEQ;
#pragma unroll
            for (int r = 0; r < 4; ++r) {
                int ilt = w * 16 + g * 4 + r;
                int d = jl - ilt + 63;
                float x = sf[fj][r] + bf2f(Pp[ilt][d]);
                if (!valid) x = -1e30f;
                sv[fj][r] = x;
                pm[r] = fmaxf(pm[r], x);
            }
        }
#pragma unroll
        for (int r = 0; r < 4; ++r) {
            float vv = pm[r];
            vv = fmaxf(vv, __shfl_xor(vv, 1));
            vv = fmaxf(vv, __shfl_xor(vv, 2));
            vv = fmaxf(vv, __shfl_xor(vv, 4));
            vv = fmaxf(vv, __shfl_xor(vv, 8));
            pm[r] = vv;
        }
        float psum[4];
#pragma unroll
        for (int r = 0; r < 4; ++r) {
            float mn = fmaxf(mrow[r], pm[r]);
            float sc = __expf(mrow[r] - mn);
            mrow[r] = mn;
            lrow[r] *= sc;
#pragma unroll
            for (int fd = 0; fd < 4; ++fd) acc[fd][r] *= sc;
            psum[r] = 0.f;
        }
#pragma unroll
        for (int fj = 0; fj < 4; ++fj) {
            int jl = fj * 16 + c;
#pragma unroll
            for (int r = 0; r < 4; ++r) {
                float p = __expf(sv[fj][r] - mrow[r]);
                psum[r] += p;
                Pl[w * 16 + g * 4 + r][jl] = f2bf(p);
            }
        }
#pragma unroll
        for (int r = 0; r < 4; ++r) {
            float vv = psum[r];
            vv += __shfl_xor(vv, 1);
            vv += __shfl_xor(vv, 2);
            vv += __shfl_xor(vv, 4);
            vv += __shfl_xor(vv, 8);
            lrow[r] += vv;
        }

        // PV
#pragma unroll
        for (int ks = 0; ks < 2; ++ks) {
            bf16x8 ap = *(bf16x8*)&Pl[w * 16 + c][ks * 32 + g * 8];
#pragma unroll
            for (int fd = 0; fd < 4; ++fd) {
                bf16x8 bv2 = *(bf16x8*)&Vt[fd * 16 + c][ks * 32 + g * 8];
                acc[fd] = __builtin_amdgcn_mfma_f32_16x16x32_bf16(ap, bv2, acc[fd], 0, 0, 0);
            }
        }
    }

    // epilogue: normalize + store ctx bf16 (B, L, D)
#pragma unroll
    for (int r = 0; r < 4; ++r) {
        int ig = i0 + w * 16 + g * 4 + r;
        if (ig < LSEQ) {
            float inv = 1.0f / lrow[r];
#pragma unroll
            for (int fd = 0; fd < 4; ++fd)
                ctx[((size_t)(b * LSEQ + ig)) * DMODEL + h * DK + fd * 16 + c] =
                    f2bf(acc[fd][r] * inv);
        }
    }
}

extern "C" void kernel_launch(void* const* d_in, const int* in_sizes, int n_in,
                              void* d_out, int out_size, void* d_ws, size_t ws_size,
                              hipStream_t stream)
{
    const float* x     = (const float*)d_in[0];
    const float* Wq    = (const float*)d_in[1];
    const float* bq    = (const float*)d_in[2];
    const float* Wk    = (const float*)d_in[3];
    const float* bk    = (const float*)d_in[4];
    const float* Wv    = (const float*)d_in[5];
    const float* bv    = (const float*)d_in[6];
    const float* Wo    = (const float*)d_in[7];
    const float* bo    = (const float*)d_in[8];
    const float* E     = (const float*)d_in[9];
    const float* gamma = (const float*)d_in[10];
    const float* beta  = (const float*)d_in[11];
    float* out = (float*)d_out;

    const size_t nTok = 8 * LSEQ;               // 8000
    const size_t nBLD = nTok * DMODEL;          // 4,096,000 elems
    short* xn_bf   = (short*)d_ws;              // 8.192 MB
    short* qb      = xn_bf + nBLD;
    short* kb      = qb + nBLD;
    short* vb      = kb + nBLD;
    short* ctx_bf  = vb + nBLD;
    short* Wqkv_bf = ctx_bf + nBLD;             // 1536*512
    short* Wo_bf   = Wqkv_bf + 1536 * 512;      // 512*512
    short* E_bf    = Wo_bf + 512 * 512;         // 1999*64

    convert_kernel<<<1149, 256, 0, stream>>>(Wq, Wk, Wv, Wo, E, Wqkv_bf, Wo_bf, E_bf);
    ln_kernel<<<(int)nTok, 256, 0, stream>>>(x, gamma, beta, xn_bf);
    gemm_bf16<0><<<dim3(12, 63), 256, 0, stream>>>(
        xn_bf, Wqkv_bf, bq, bk, bv, qb, kb, vb, nullptr, nullptr);
    attn_mfma<<<dim3((LSEQ + TI - 1) / TI, NHEAD, 8), 256, 0, stream>>>(
        qb, kb, vb, E_bf, ctx_bf);
    gemm_bf16<1><<<dim3(4, 63), 256, 0, stream>>>(
        ctx_bf, Wo_bf, bo, nullptr, nullptr, nullptr, nullptr, nullptr, out, x);
}